// Round 10
// baseline (641.466 us; speedup 1.0000x reference)
//
#include <hip/hip_runtime.h>
#include <math.h>

#define BN_EPS 1e-5f

typedef float f32x4 __attribute__((ext_vector_type(4)));
typedef short s16x8 __attribute__((ext_vector_type(8)));

__device__ __forceinline__ unsigned short f2bf(float f) {
    unsigned u = __builtin_bit_cast(unsigned, f);
    u = u + 0x7FFFu + ((u >> 16) & 1u);
    return (unsigned short)(u >> 16);
}
__device__ __forceinline__ float bf2f(unsigned short s) {
    unsigned u = ((unsigned)s) << 16;
    return __builtin_bit_cast(float, u);
}

__device__ __forceinline__ void gload16(const void* g, void* l) {
    __builtin_amdgcn_global_load_lds((const __attribute__((address_space(1))) unsigned int*)g,
                                     (__attribute__((address_space(3))) unsigned int*)l,
                                     16, 0, 0);
}

// ================ 3-NN body: per-slice exact top-3 (consecutive-j chunks, b128 LDS, med3 insert) ====
template<int CAND, int CHUNK, int STRIDE, bool PART>
__device__ __forceinline__ void knn_body(const float* __restrict__ pd,
                                         const float* __restrict__ ps,
                                         int N1, int N2total, int grp, int slice, int b,
                                         int* __restrict__ idx, float* __restrict__ w,
                                         unsigned long long* __restrict__ pk, int nslice,
                                         float* spx, float* spy, float* spz) {
    int tid = threadIdx.x;
    int cbase = slice * CAND;
    for (int g = tid; g < CAND; g += 256) {
        int s = g / CHUNK, off = g % CHUNK;
        size_t base = ((size_t)b * N2total + cbase + g) * 3;
        spx[s * STRIDE + off] = ps[base];
        spy[s * STRIDE + off] = ps[base + 1];
        spz[s * STRIDE + off] = ps[base + 2];
    }
    __syncthreads();
    int sub = tid & 7;
    int n = grp * 32 + (tid >> 3);
    size_t pb = ((size_t)b * N1 + n) * 3;
    float px = pd[pb], py = pd[pb + 1], pz = pd[pb + 2];
    float dd0 = 3.4e38f, dd1 = 3.4e38f, dd2 = 3.4e38f;
    int ii0 = 0, ii1 = 0, ii2 = 0;
    const float* rx = spx + sub * STRIDE;
    const float* ry = spy + sub * STRIDE;
    const float* rz = spz + sub * STRIDE;
    int jbase = cbase + sub * CHUNK;
    for (int t = 0; t < CHUNK; t += 4) {
        f32x4 x4 = *(const f32x4*)(rx + t);
        f32x4 y4 = *(const f32x4*)(ry + t);
        f32x4 z4 = *(const f32x4*)(rz + t);
#pragma unroll
        for (int e = 0; e < 4; e++) {
            float dx = px - x4[e], dy = py - y4[e], dz = pz - z4[e];
            float d = dx * dx + dy * dy + dz * dz;
            int j = jbase + t + e;
            bool C0 = d < dd0, C1 = d < dd1, C2 = d < dd2;
            int ni2 = C1 ? ii1 : (C2 ? j : ii2);
            int ni1 = C0 ? ii0 : (C1 ? j : ii1);
            int ni0 = C0 ? j : ii0;
            dd2 = __builtin_amdgcn_fmed3f(d, dd1, dd2);
            dd1 = __builtin_amdgcn_fmed3f(d, dd0, dd1);
            dd0 = fminf(d, dd0);
            ii0 = ni0; ii1 = ni1; ii2 = ni2;
        }
    }
    unsigned long long k0 = ((unsigned long long)__builtin_bit_cast(unsigned, dd0) << 32) | (unsigned)ii0;
    unsigned long long k1 = ((unsigned long long)__builtin_bit_cast(unsigned, dd1) << 32) | (unsigned)ii1;
    unsigned long long k2 = ((unsigned long long)__builtin_bit_cast(unsigned, dd2) << 32) | (unsigned)ii2;
#pragma unroll
    for (int m = 1; m < 8; m <<= 1) {
        unsigned long long e0, e1, e2;
        { int lo = __shfl_xor((int)(unsigned)(k0 & 0xFFFFFFFFull), m), hi = __shfl_xor((int)(unsigned)(k0 >> 32), m);
          e0 = ((unsigned long long)(unsigned)hi << 32) | (unsigned)lo; }
        { int lo = __shfl_xor((int)(unsigned)(k1 & 0xFFFFFFFFull), m), hi = __shfl_xor((int)(unsigned)(k1 >> 32), m);
          e1 = ((unsigned long long)(unsigned)hi << 32) | (unsigned)lo; }
        { int lo = __shfl_xor((int)(unsigned)(k2 & 0xFFFFFFFFull), m), hi = __shfl_xor((int)(unsigned)(k2 >> 32), m);
          e2 = ((unsigned long long)(unsigned)hi << 32) | (unsigned)lo; }
        unsigned long long t0, t1;
        t0 = k0 > e0 ? k0 : e0; k0 = k0 < e0 ? k0 : e0; t1 = k1 > t0 ? k1 : t0; k1 = k1 < t0 ? k1 : t0; k2 = k2 < t1 ? k2 : t1;
        t0 = k0 > e1 ? k0 : e1; k0 = k0 < e1 ? k0 : e1; t1 = k1 > t0 ? k1 : t0; k1 = k1 < t0 ? k1 : t0; k2 = k2 < t1 ? k2 : t1;
        t0 = k0 > e2 ? k0 : e2; k0 = k0 < e2 ? k0 : e2; t1 = k1 > t0 ? k1 : t0; k1 = k1 < t0 ? k1 : t0; k2 = k2 < t1 ? k2 : t1;
    }
    if (sub == 0) {
        if (PART) {
            size_t o = ((size_t)(b * N1 + n) * nslice + slice) * 3;
            pk[o] = k0; pk[o + 1] = k1; pk[o + 2] = k2;
        } else {
            float f0 = __builtin_bit_cast(float, (unsigned)(k0 >> 32));
            float f1 = __builtin_bit_cast(float, (unsigned)(k1 >> 32));
            float f2 = __builtin_bit_cast(float, (unsigned)(k2 >> 32));
            float w0 = 1.f / (f0 + 1e-8f), w1 = 1.f / (f1 + 1e-8f), w2 = 1.f / (f2 + 1e-8f);
            float s = 1.f / (w0 + w1 + w2);
            size_t o = ((size_t)b * N1 + n) * 3;
            idx[o] = (int)(unsigned)(k0 & 0xFFFFFFFFull);
            idx[o + 1] = (int)(unsigned)(k1 & 0xFFFFFFFFull);
            idx[o + 2] = (int)(unsigned)(k2 & 0xFFFFFFFFull);
            w[o] = w0 * s; w[o + 1] = w1 * s; w[o + 2] = w2 * s;
        }
    }
}

// ================ prep: fused transposes(+cls) | KNN slices | input-only weight preps ================
__global__ __launch_bounds__(256) void prep(const float* __restrict__ f1,
                                            const float* __restrict__ f2,
                                            const float* __restrict__ f3,
                                            const float* __restrict__ f4,
                                            unsigned short* __restrict__ F1T,
                                            unsigned short* __restrict__ F2T,
                                            unsigned short* __restrict__ F3T,
                                            unsigned short* __restrict__ F4T,
                                            const int* __restrict__ lbl,
                                            const float* __restrict__ Wc1,
                                            const float* __restrict__ gc,
                                            const float* __restrict__ bc,
                                            const float* __restrict__ Wc2,
                                            const float* __restrict__ p1,
                                            const float* __restrict__ p2,
                                            const float* __restrict__ p3,
                                            const float* __restrict__ p4,
                                            int* __restrict__ idx1, float* __restrict__ w1,
                                            int* __restrict__ idx2, float* __restrict__ w2,
                                            unsigned long long* __restrict__ pk0,
                                            const float* __restrict__ Ws2a,
                                            unsigned short* __restrict__ WI2, float* __restrict__ BIA2,
                                            unsigned short* __restrict__ WS2, float* __restrict__ BIS2,
                                            const float* __restrict__ Ws1a,
                                            unsigned short* __restrict__ WS1, float* __restrict__ BIS1,
                                            const float* __restrict__ Ws0a,
                                            unsigned short* __restrict__ WS0, float* __restrict__ BIS0) {
    __shared__ float t[32][33];
    __shared__ float clsv[32];
    __shared__ float hsh[4][64];
    __shared__ float actsh[4][64];
    __shared__ float spx[8 * 72], spy[8 * 72], spz[8 * 72];
    int bx = blockIdx.x, b = blockIdx.y;
    int tid = threadIdx.x;

    if (bx >= 3024) {  // weight-prep segments (input-only, no BN fold -> bias 0)
        if (b != 0) return;
        int wx = bx - 3024;
        const float* W; unsigned short* Wb; float* bias; int Ktot, kOff, Ks, m;
        if (wx < 512)       { W = Ws2a; Wb = WI2; bias = BIA2; Ktot = 1536; kOff = 512; Ks = 1024; m = wx; }
        else if (wx < 1024) { W = Ws2a; Wb = WS2; bias = BIS2; Ktot = 1536; kOff = 0;   Ks = 512;  m = wx - 512; }
        else if (wx < 1280) { W = Ws1a; Wb = WS1; bias = BIS1; Ktot = 768;  kOff = 0;   Ks = 256;  m = wx - 1024; }
        else                { W = Ws0a; Wb = WS0; bias = BIS0; Ktot = 384;  kOff = 0;   Ks = 128;  m = wx - 1280; }
        for (int k = tid; k < Ks; k += 256)
            Wb[(size_t)m * Ks + k] = f2bf(W[(size_t)m * Ktot + kOff + k]);
        if (tid == 0) bias[m] = 0.f;
        return;
    }
    if (bx >= 1920) {  // KNN segments
        int kx = bx - 1920;
        if (kx < 16)      knn_body<128, 16, 24, false>(p3, p4, 512, 128, kx, 0, b, idx2, w2, nullptr, 1, spx, spy, spz);
        else if (kx < 80) knn_body<512, 64, 72, false>(p2, p3, 2048, 512, kx - 16, 0, b, idx1, w1, nullptr, 1, spx, spy, spz);
        else {
            int u = kx - 80;
            knn_body<512, 64, 72, true>(p1, p2, 8192, 2048, u >> 2, u & 3, b, nullptr, nullptr, pk0, 4, spx, spy, spz);
        }
        return;
    }
    // transpose segments
    const float* in; unsigned short* out; int C, N, nx, seg; bool docls = false;
    if (bx < 128)      { in = f4; out = F4T; C = 1024; N = 128;  nx = 4;   seg = bx; }
    else if (bx < 384) { in = f3; out = F3T; C = 512;  N = 512;  nx = 16;  seg = bx - 128; }
    else if (bx < 896) { in = f2; out = F2T; C = 256;  N = 2048; nx = 64;  seg = bx - 384; }
    else               { in = f1; out = F1T; C = 128;  N = 8192; nx = 256; seg = bx - 896; docls = true; }
    int n0 = (seg % nx) * 32, c0 = (seg / nx) * 32;
    if (docls) {
        { int b2 = tid >> 6, c = tid & 63; hsh[b2][c] = Wc1[c * 16 + lbl[b2]]; }
        __syncthreads();
        if (tid < 64) {
            int c = tid;
            float m = 0.f;
            for (int b2 = 0; b2 < 4; b2++) m += hsh[b2][c];
            m *= 0.25f;
            float v = 0.f;
            for (int b2 = 0; b2 < 4; b2++) { float d = hsh[b2][c] - m; v += d * d; }
            v *= 0.25f;
            float sc = gc[c] * rsqrtf(v + BN_EPS);
            float sh = bc[c] - m * sc;
            for (int b2 = 0; b2 < 4; b2++) {
                float x = hsh[b2][c] * sc + sh;
                actsh[b2][c] = 0.5f * x * (1.f + erff(x * 0.70710678118654752f));
            }
        }
        __syncthreads();
        if (tid < 32) {
            float s = 0.f;
            for (int c = 0; c < 64; c++) s += Wc2[(size_t)(c0 + tid) * 64 + c] * actsh[b][c];
            clsv[tid] = s;
        }
        __syncthreads();
    }
    int i = tid & 31, jj = tid >> 5;
#pragma unroll
    for (int j = jj; j < 32; j += 8) {
        float v = in[((size_t)b * C + c0 + j) * N + n0 + i];
        if (docls) v += clsv[j];
        t[j][i] = v;
    }
    __syncthreads();
    int j2 = tid & 31, i2b = tid >> 5;
#pragma unroll
    for (int i2 = i2b; i2 < 32; i2 += 8)
        out[((size_t)b * N + n0 + i2) * C + c0 + j2] = f2bf(t[j2][i2]);
}

// ================ 3-NN merge: combine 4 slice-partials per query (exact u64 order) ================
__global__ __launch_bounds__(256) void knn_merge(const unsigned long long* __restrict__ pk,
                                                 int* __restrict__ idx, float* __restrict__ w,
                                                 int NQ) {
    int q = blockIdx.x * 256 + threadIdx.x;
    if (q >= NQ) return;
    const unsigned long long* p = pk + (size_t)q * 12;
    unsigned long long k0 = ~0ull, k1 = ~0ull, k2 = ~0ull;
#pragma unroll
    for (int i = 0; i < 12; i++) {
        unsigned long long c = p[i];
        unsigned long long t0 = k0 > c ? k0 : c; k0 = k0 < c ? k0 : c;
        unsigned long long t1 = k1 > t0 ? k1 : t0; k1 = k1 < t0 ? k1 : t0;
        k2 = k2 < t1 ? k2 : t1;
    }
    float f0 = __builtin_bit_cast(float, (unsigned)(k0 >> 32));
    float f1 = __builtin_bit_cast(float, (unsigned)(k1 >> 32));
    float f2 = __builtin_bit_cast(float, (unsigned)(k2 >> 32));
    float w0 = 1.f / (f0 + 1e-8f), w1 = 1.f / (f1 + 1e-8f), w2 = 1.f / (f2 + 1e-8f);
    float s = 1.f / (w0 + w1 + w2);
    size_t o = (size_t)q * 3;
    idx[o] = (int)(unsigned)(k0 & 0xFFFFFFFFull);
    idx[o + 1] = (int)(unsigned)(k1 & 0xFFFFFFFFull);
    idx[o + 2] = (int)(unsigned)(k2 & 0xFFFFFFFFull);
    w[o] = w0 * s; w[o + 1] = w1 * s; w[o + 2] = w2 * s;
}

// ================ weight prep (BN fold): slice [kOff,kOff+Ks), W*sc, bias = W.sh ================
__global__ __launch_bounds__(256) void wprep(const float* __restrict__ W,
                                             const float* __restrict__ sc,
                                             const float* __restrict__ sh,
                                             unsigned short* __restrict__ Wb,
                                             float* __restrict__ bias,
                                             int Ktot, int kOff, int Ks) {
    int m = blockIdx.x;
    int tid = threadIdx.x;
    float bsum = 0.f;
    for (int k = tid; k < Ks; k += 256) {
        float wv = W[(size_t)m * Ktot + kOff + k];
        Wb[(size_t)m * Ks + k] = f2bf(wv * sc[k]);
        bsum += wv * sh[k];
    }
    __shared__ float ls[256];
    ls[tid] = bsum;
    __syncthreads();
    for (int o = 128; o > 0; o >>= 1) {
        if (tid < o) ls[tid] += ls[tid + o];
        __syncthreads();
    }
    if (tid == 0) bias[m] = ls[0];
}

// ================ bf16 MFMA GEMM 64x64, dbuf + global_load_lds + counted vmcnt ================
// GATHER: epilogue adds interp gather from G (conv'd sparse). STATS: partial stats + last-block BN finalize.
template<bool GATHER, bool STATS>
__global__ __launch_bounds__(256) void gemm64(const unsigned short* __restrict__ XT,
                                              const unsigned short* __restrict__ Wb,
                                              const float* __restrict__ bias,
                                              const unsigned short* __restrict__ G,
                                              const int* __restrict__ gidx,
                                              const float* __restrict__ gw,
                                              int n1shift, int N2loc,
                                              unsigned short* __restrict__ OutT,
                                              float* __restrict__ ps,
                                              const float* __restrict__ bng,
                                              const float* __restrict__ bnb,
                                              float* __restrict__ scOut,
                                              float* __restrict__ shOut,
                                              unsigned* __restrict__ cnt, int Npts,
                                              int BN, int K, int M) {
    __shared__ unsigned short As[2][64 * 32];
    __shared__ unsigned short Bs[2][64 * 32];
    __shared__ float sred[2][2][32][2];
    __shared__ int lastFlag;
    int tid = threadIdx.x;
    int lane = tid & 63, wid = tid >> 6;
    int wn = wid & 1, wm = wid >> 1;
    int bx = blockIdx.x, by = blockIdx.y;

    int srow = (wid << 4) + (lane >> 2);
    int skcol = (lane & 3) << 3;
    const unsigned short* gA = XT + (size_t)(bx * 64 + srow) * K + skcol;
    const unsigned short* gB = Wb + (size_t)(by * 64 + srow) * K + skcol;

    int r16 = lane & 15, q = lane >> 4;
    f32x4 acc[2][2];
#pragma unroll
    for (int i = 0; i < 2; i++)
#pragma unroll
        for (int j = 0; j < 2; j++) acc[i][j] = (f32x4)0.f;

    int nt = K >> 5;
    gload16(gA, &As[0][wid * 512]);
    gload16(gB, &Bs[0][wid * 512]);

    for (int t = 0; t < nt; t++) {
        int cur = t & 1;
        if (t + 1 < nt) {
            int k0 = (t + 1) << 5;
            gload16(gA + k0, &As[cur ^ 1][wid * 512]);
            gload16(gB + k0, &Bs[cur ^ 1][wid * 512]);
            asm volatile("s_waitcnt vmcnt(2)" ::: "memory");
        } else {
            asm volatile("s_waitcnt vmcnt(0)" ::: "memory");
        }
        __syncthreads();
        s16x8 afr[2], bfr[2];
        afr[0] = *(const s16x8*)&As[cur][(wn * 32 + r16) * 32 + q * 8];
        afr[1] = *(const s16x8*)&As[cur][(wn * 32 + 16 + r16) * 32 + q * 8];
        bfr[0] = *(const s16x8*)&Bs[cur][(wm * 32 + r16) * 32 + q * 8];
        bfr[1] = *(const s16x8*)&Bs[cur][(wm * 32 + 16 + r16) * 32 + q * 8];
        asm volatile("s_waitcnt lgkmcnt(0)" ::: "memory");
        __builtin_amdgcn_sched_barrier(0);
        __syncthreads();
#pragma unroll
        for (int i = 0; i < 2; i++)
#pragma unroll
            for (int j = 0; j < 2; j++)
                acc[i][j] = __builtin_amdgcn_mfma_f32_16x16x32_bf16(afr[i], bfr[j], acc[i][j], 0, 0, 0);
    }

    if (GATHER) {
#pragma unroll
        for (int i = 0; i < 2; i++)
#pragma unroll
            for (int rr = 0; rr < 4; rr++) {
                int R = bx * 64 + wn * 32 + i * 16 + q * 4 + rr;
                size_t ob = (size_t)R * 3;
                int i0 = gidx[ob], i1 = gidx[ob + 1], i2 = gidx[ob + 2];
                float w0 = gw[ob], w1 = gw[ob + 1], w2 = gw[ob + 2];
                size_t gbase = (size_t)(R >> n1shift) * N2loc;
                const unsigned short* g0 = G + (gbase + i0) * M + by * 64;
                const unsigned short* g1 = G + (gbase + i1) * M + by * 64;
                const unsigned short* g2 = G + (gbase + i2) * M + by * 64;
#pragma unroll
                for (int j = 0; j < 2; j++) {
                    int mcol = wm * 32 + j * 16 + r16;
                    acc[i][j][rr] += w0 * bf2f(g0[mcol]) + w1 * bf2f(g1[mcol]) + w2 * bf2f(g2[mcol]);
                }
            }
    }

    int mc0 = by * 64 + wm * 32 + r16;
    float bv[2] = { bias[mc0], bias[mc0 + 16] };
    unsigned short* Ob = OutT + (size_t)(bx * 64) * M + by * 64;
    float s[2] = {0.f, 0.f}, qq[2] = {0.f, 0.f};
#pragma unroll
    for (int i = 0; i < 2; i++) {
#pragma unroll
        for (int j = 0; j < 2; j++) {
            int mcol = wm * 32 + j * 16 + r16;
#pragma unroll
            for (int r = 0; r < 4; r++) {
                float v = acc[i][j][r] + bv[j];
                s[j] += v; qq[j] += v * v;
                int n = wn * 32 + i * 16 + q * 4 + r;
                Ob[(size_t)n * M + mcol] = f2bf(v);
            }
        }
    }
    if (STATS) {
#pragma unroll
        for (int j = 0; j < 2; j++) {
            s[j] += __shfl_xor(s[j], 16); s[j] += __shfl_xor(s[j], 32);
            qq[j] += __shfl_xor(qq[j], 16); qq[j] += __shfl_xor(qq[j], 32);
        }
        if (lane < 16) {
#pragma unroll
            for (int j = 0; j < 2; j++) {
                sred[wn][wm][j * 16 + lane][0] = s[j];
                sred[wn][wm][j * 16 + lane][1] = qq[j];
            }
        }
        __syncthreads();
        if (tid < 64) {
            int wmm = tid >> 5, c = tid & 31;
            float ssum = sred[0][wmm][c][0] + sred[1][wmm][c][0];
            float qsum = sred[0][wmm][c][1] + sred[1][wmm][c][1];
            size_t blin = (size_t)by * gridDim.x + bx;
            ps[blin * 128 + tid * 2] = ssum;
            ps[blin * 128 + tid * 2 + 1] = qsum;
        }
        __syncthreads();
        if (tid == 0) {
            __threadfence();
            unsigned total = gridDim.x * gridDim.y;
            unsigned old = atomicAdd(cnt, 1u);
            lastFlag = (old == total - 1) ? 1 : 0;
        }
        __syncthreads();
        if (lastFlag) {
            __threadfence();
            int gx = gridDim.x;
            for (int m = tid; m < M; m += 256) {
                int byy = m >> 6, ch = m & 63;
                float ssum = 0.f, qsum = 0.f;
                for (int bxi = 0; bxi < gx; bxi++) {
                    size_t blin = (size_t)byy * gx + bxi;
                    ssum += ps[blin * 128 + ch * 2];
                    qsum += ps[blin * 128 + ch * 2 + 1];
                }
                float inv = 1.f / (float)Npts;
                float mean = ssum * inv;
                float var = fmaxf(qsum * inv - mean * mean, 0.f);
                float scale = bng[m] * rsqrtf(var + BN_EPS);
                scOut[m] = scale;
                shOut[m] = bnb[m] - mean * scale;
            }
            if (tid == 0) *cnt = 0u;
        }
    }
}

// ================ final: (B,N,M) bf16 -> (B,M,N) fp32 with BN affine ================
__global__ __launch_bounds__(256) void out_bn_tr(const unsigned short* __restrict__ in,
                                                 float* __restrict__ out,
                                                 const float* __restrict__ sc,
                                                 const float* __restrict__ sh,
                                                 int M, int N) {
    __shared__ float t[32][33];
    int b = blockIdx.z;
    int n0 = blockIdx.x * 32, m0 = blockIdx.y * 32;
    int j = threadIdx.x & 31, ii = threadIdx.x >> 5;
#pragma unroll
    for (int i = ii; i < 32; i += 8)
        t[i][j] = bf2f(in[((size_t)b * N + n0 + i) * M + m0 + j]);
    __syncthreads();
    int i2 = threadIdx.x & 31, j2b = threadIdx.x >> 5;
#pragma unroll
    for (int j2 = j2b; j2 < 32; j2 += 8)
        out[((size_t)b * M + m0 + j2) * N + n0 + i2] = t[i2][j2] * sc[m0 + j2] + sh[m0 + j2];
}

extern "C" void kernel_launch(void* const* d_in, const int* in_sizes, int n_in,
                              void* d_out, int out_size, void* d_ws, size_t ws_size,
                              hipStream_t stream) {
    const float* p1 = (const float*)d_in[1];
    const float* p2 = (const float*)d_in[2];
    const float* p3 = (const float*)d_in[3];
    const float* p4 = (const float*)d_in[4];
    const float* f1 = (const float*)d_in[5];
    const float* f2 = (const float*)d_in[6];
    const float* f3 = (const float*)d_in[7];
    const float* f4 = (const float*)d_in[8];
    const int* cls = (const int*)d_in[9];
    const float* Wc1 = (const float*)d_in[10];
    const float* gc  = (const float*)d_in[11];
    const float* bc  = (const float*)d_in[12];
    const float* Wc2 = (const float*)d_in[13];
    const float* Ws2a = (const float*)d_in[14];
    const float* gs2a = (const float*)d_in[15];
    const float* bs2a = (const float*)d_in[16];
    const float* Ws2b = (const float*)d_in[17];
    const float* gs2b = (const float*)d_in[18];
    const float* bs2b = (const float*)d_in[19];
    const float* Ws1a = (const float*)d_in[20];
    const float* gs1a = (const float*)d_in[21];
    const float* bs1a = (const float*)d_in[22];
    const float* Ws1b = (const float*)d_in[23];
    const float* gs1b = (const float*)d_in[24];
    const float* bs1b = (const float*)d_in[25];
    const float* Ws0a = (const float*)d_in[26];
    const float* gs0a = (const float*)d_in[27];
    const float* bs0a = (const float*)d_in[28];
    const float* Ws0b = (const float*)d_in[29];
    const float* gs0b = (const float*)d_in[30];
    const float* bs0b = (const float*)d_in[31];

    char* ws = (char*)d_ws;
    size_t off = 0;
    auto alloc = [&](size_t bytes) { char* p = ws + off; off += (bytes + 255) & ~(size_t)255; return p; };
    unsigned short* F4T = (unsigned short*)alloc((size_t)4 * 128 * 1024 * 2);
    unsigned short* F3T = (unsigned short*)alloc((size_t)4 * 512 * 512 * 2);
    unsigned short* F2T = (unsigned short*)alloc((size_t)4 * 2048 * 256 * 2);
    unsigned short* F1T = (unsigned short*)alloc((size_t)4 * 8192 * 128 * 2);
    unsigned short* G2T = (unsigned short*)alloc((size_t)4 * 128 * 512 * 2);
    unsigned short* G1T = (unsigned short*)alloc((size_t)4 * 512 * 256 * 2);
    unsigned short* G0T = (unsigned short*)alloc((size_t)4 * 2048 * 128 * 2);
    unsigned short* YA  = (unsigned short*)alloc((size_t)4 * 8192 * 128 * 2);
    unsigned short* FN2 = (unsigned short*)alloc((size_t)4 * 512 * 512 * 2);
    unsigned short* FN1 = (unsigned short*)alloc((size_t)4 * 2048 * 256 * 2);
    unsigned short* XO  = (unsigned short*)alloc((size_t)4 * 8192 * 128 * 2);
    unsigned short* WI2 = (unsigned short*)alloc((size_t)512 * 1024 * 2);
    unsigned short* WS2 = (unsigned short*)alloc((size_t)512 * 512 * 2);
    unsigned short* WB2b = (unsigned short*)alloc((size_t)512 * 512 * 2);
    unsigned short* WI1 = (unsigned short*)alloc((size_t)256 * 512 * 2);
    unsigned short* WS1 = (unsigned short*)alloc((size_t)256 * 256 * 2);
    unsigned short* WB1b = (unsigned short*)alloc((size_t)256 * 256 * 2);
    unsigned short* WI0 = (unsigned short*)alloc((size_t)128 * 256 * 2);
    unsigned short* WS0 = (unsigned short*)alloc((size_t)128 * 128 * 2);
    unsigned short* WB0b = (unsigned short*)alloc((size_t)128 * 128 * 2);
    float* BIA2 = (float*)alloc(512 * 4); float* BIS2 = (float*)alloc(512 * 4);
    float* BI2b = (float*)alloc(512 * 4);
    float* BIA1 = (float*)alloc(256 * 4); float* BIS1 = (float*)alloc(256 * 4);
    float* BI1b = (float*)alloc(256 * 4);
    float* BIA0 = (float*)alloc(128 * 4); float* BIS0 = (float*)alloc(128 * 4);
    float* BI0b = (float*)alloc(128 * 4);
    int*   IDX0 = (int*)alloc((size_t)4 * 8192 * 3 * 4);
    float* WGT0 = (float*)alloc((size_t)4 * 8192 * 3 * 4);
    int*   IDX1 = (int*)alloc((size_t)4 * 2048 * 3 * 4);
    float* WGT1 = (float*)alloc((size_t)4 * 2048 * 3 * 4);
    int*   IDX2 = (int*)alloc((size_t)4 * 512 * 3 * 4);
    float* WGT2 = (float*)alloc((size_t)4 * 512 * 3 * 4);
    unsigned long long* PK0 = (unsigned long long*)alloc((size_t)4 * 8192 * 4 * 3 * 8);
    float* PS = (float*)alloc((size_t)1024 * 128 * 4);
    unsigned* CNT = (unsigned*)alloc(8 * 4);
    float* SC2a = (float*)alloc(512 * 4); float* SH2a = (float*)alloc(512 * 4);
    float* SC2b = (float*)alloc(512 * 4); float* SH2b = (float*)alloc(512 * 4);
    float* SC1a = (float*)alloc(512 * 4); float* SH1a = (float*)alloc(512 * 4);
    float* SC1b = (float*)alloc(512 * 4); float* SH1b = (float*)alloc(512 * 4);
    float* SC0a = (float*)alloc(512 * 4); float* SH0a = (float*)alloc(512 * 4);
    float* SC0b = (float*)alloc(512 * 4); float* SH0b = (float*)alloc(512 * 4);
    float* OUT = (float*)d_out;

    hipMemsetAsync(CNT, 0, 8 * 4, stream);

    // 1) all input-only work in one dispatch
    prep<<<dim3(4432, 4), 256, 0, stream>>>(f1, f2, f3, f4, F1T, F2T, F3T, F4T,
                                            cls, Wc1, gc, bc, Wc2,
                                            p1, p2, p3, p4,
                                            IDX1, WGT1, IDX2, WGT2, PK0,
                                            Ws2a, WI2, BIA2, WS2, BIS2,
                                            Ws1a, WS1, BIS1, Ws0a, WS0, BIS0);
    knn_merge<<<(4 * 8192) / 256, 256, 0, stream>>>(PK0, IDX0, WGT0, 4 * 8192);

    // ---- stage s2
    gemm64<false, false><<<dim3(8, 8), 256, 0, stream>>>(F4T, WI2, BIA2, nullptr, nullptr, nullptr, 0, 0,
                                                         G2T, nullptr, nullptr, nullptr, nullptr, nullptr, nullptr, 0,
                                                         512, 1024, 512);
    gemm64<true, true><<<dim3(32, 8), 256, 0, stream>>>(F3T, WS2, BIS2, G2T, IDX2, WGT2, 9, 128,
                                                        YA, PS, gs2a, bs2a, SC2a, SH2a, CNT + 0, 2048,
                                                        2048, 512, 512);
    wprep<<<512, 256, 0, stream>>>(Ws2b, SC2a, SH2a, WB2b, BI2b, 512, 0, 512);
    gemm64<false, true><<<dim3(32, 8), 256, 0, stream>>>(YA, WB2b, BI2b, nullptr, nullptr, nullptr, 0, 0,
                                                         FN2, PS, gs2b, bs2b, SC2b, SH2b, CNT + 1, 2048,
                                                         2048, 512, 512);

    // ---- stage s1
    wprep<<<256, 256, 0, stream>>>(Ws1a, SC2b, SH2b, WI1, BIA1, 768, 256, 512);
    gemm64<false, false><<<dim3(32, 4), 256, 0, stream>>>(FN2, WI1, BIA1, nullptr, nullptr, nullptr, 0, 0,
                                                          G1T, nullptr, nullptr, nullptr, nullptr, nullptr, nullptr, 0,
                                                          2048, 512, 256);
    gemm64<true, true><<<dim3(128, 4), 256, 0, stream>>>(F2T, WS1, BIS1, G1T, IDX1, WGT1, 11, 512,
                                                         YA, PS, gs1a, bs1a, SC1a, SH1a, CNT + 2, 8192,
                                                         8192, 256, 256);
    wprep<<<256, 256, 0, stream>>>(Ws1b, SC1a, SH1a, WB1b, BI1b, 256, 0, 256);
    gemm64<false, true><<<dim3(128, 4), 256, 0, stream>>>(YA, WB1b, BI1b, nullptr, nullptr, nullptr, 0, 0,
                                                          FN1, PS, gs1b, bs1b, SC1b, SH1b, CNT + 3, 8192,
                                                          8192, 256, 256);

    // ---- stage s0
    wprep<<<128, 256, 0, stream>>>(Ws0a, SC1b, SH1b, WI0, BIA0, 384, 128, 256);
    gemm64<false, false><<<dim3(128, 2), 256, 0, stream>>>(FN1, WI0, BIA0, nullptr, nullptr, nullptr, 0, 0,
                                                           G0T, nullptr, nullptr, nullptr, nullptr, nullptr, nullptr, 0,
                                                           8192, 256, 128);
    gemm64<true, true><<<dim3(512, 2), 256, 0, stream>>>(F1T, WS0, BIS0, G0T, IDX0, WGT0, 13, 2048,
                                                         YA, PS, gs0a, bs0a, SC0a, SH0a, CNT + 4, 32768,
                                                         32768, 128, 128);
    wprep<<<128, 256, 0, stream>>>(Ws0b, SC0a, SH0a, WB0b, BI0b, 128, 0, 128);
    gemm64<false, true><<<dim3(512, 2), 256, 0, stream>>>(YA, WB0b, BI0b, nullptr, nullptr, nullptr, 0, 0,
                                                          XO, PS, gs0b, bs0b, SC0b, SH0b, CNT + 5, 32768,
                                                          32768, 128, 128);

    out_bn_tr<<<dim3(8192 / 32, 128 / 32, 4), 256, 0, stream>>>(XO, OUT, SC0b, SH0b, 128, 8192);
}

// Round 11
// 186.707 us; speedup vs baseline: 3.4357x; 3.4357x over previous
//
#include <hip/hip_runtime.h>
#include <math.h>

#define BN_EPS 1e-5f

typedef float f32x4 __attribute__((ext_vector_type(4)));
typedef short s16x8 __attribute__((ext_vector_type(8)));

__device__ __forceinline__ unsigned short f2bf(float f) {
    unsigned u = __builtin_bit_cast(unsigned, f);
    u = u + 0x7FFFu + ((u >> 16) & 1u);
    return (unsigned short)(u >> 16);
}
__device__ __forceinline__ float bf2f(unsigned short s) {
    unsigned u = ((unsigned)s) << 16;
    return __builtin_bit_cast(float, u);
}

__device__ __forceinline__ void gload16(const void* g, void* l) {
    __builtin_amdgcn_global_load_lds((const __attribute__((address_space(1))) unsigned int*)g,
                                     (__attribute__((address_space(3))) unsigned int*)l,
                                     16, 0, 0);
}

// ================ 3-NN body: per-slice exact top-3 (consecutive-j chunks, b128 LDS, med3 insert) ====
template<int CAND, int CHUNK, int STRIDE, bool PART>
__device__ __forceinline__ void knn_body(const float* __restrict__ pd,
                                         const float* __restrict__ ps,
                                         int N1, int N2total, int grp, int slice, int b,
                                         int* __restrict__ idx, float* __restrict__ w,
                                         unsigned long long* __restrict__ pk, int nslice,
                                         float* spx, float* spy, float* spz) {
    int tid = threadIdx.x;
    int cbase = slice * CAND;
    for (int g = tid; g < CAND; g += 256) {
        int s = g / CHUNK, off = g % CHUNK;
        size_t base = ((size_t)b * N2total + cbase + g) * 3;
        spx[s * STRIDE + off] = ps[base];
        spy[s * STRIDE + off] = ps[base + 1];
        spz[s * STRIDE + off] = ps[base + 2];
    }
    __syncthreads();
    int sub = tid & 7;
    int n = grp * 32 + (tid >> 3);
    size_t pb = ((size_t)b * N1 + n) * 3;
    float px = pd[pb], py = pd[pb + 1], pz = pd[pb + 2];
    float dd0 = 3.4e38f, dd1 = 3.4e38f, dd2 = 3.4e38f;
    int ii0 = 0, ii1 = 0, ii2 = 0;
    const float* rx = spx + sub * STRIDE;
    const float* ry = spy + sub * STRIDE;
    const float* rz = spz + sub * STRIDE;
    int jbase = cbase + sub * CHUNK;
    for (int t = 0; t < CHUNK; t += 4) {
        f32x4 x4 = *(const f32x4*)(rx + t);
        f32x4 y4 = *(const f32x4*)(ry + t);
        f32x4 z4 = *(const f32x4*)(rz + t);
#pragma unroll
        for (int e = 0; e < 4; e++) {
            float dx = px - x4[e], dy = py - y4[e], dz = pz - z4[e];
            float d = dx * dx + dy * dy + dz * dz;
            int j = jbase + t + e;
            bool C0 = d < dd0, C1 = d < dd1, C2 = d < dd2;
            int ni2 = C1 ? ii1 : (C2 ? j : ii2);
            int ni1 = C0 ? ii0 : (C1 ? j : ii1);
            int ni0 = C0 ? j : ii0;
            dd2 = __builtin_amdgcn_fmed3f(d, dd1, dd2);
            dd1 = __builtin_amdgcn_fmed3f(d, dd0, dd1);
            dd0 = fminf(d, dd0);
            ii0 = ni0; ii1 = ni1; ii2 = ni2;
        }
    }
    unsigned long long k0 = ((unsigned long long)__builtin_bit_cast(unsigned, dd0) << 32) | (unsigned)ii0;
    unsigned long long k1 = ((unsigned long long)__builtin_bit_cast(unsigned, dd1) << 32) | (unsigned)ii1;
    unsigned long long k2 = ((unsigned long long)__builtin_bit_cast(unsigned, dd2) << 32) | (unsigned)ii2;
#pragma unroll
    for (int m = 1; m < 8; m <<= 1) {
        unsigned long long e0, e1, e2;
        { int lo = __shfl_xor((int)(unsigned)(k0 & 0xFFFFFFFFull), m), hi = __shfl_xor((int)(unsigned)(k0 >> 32), m);
          e0 = ((unsigned long long)(unsigned)hi << 32) | (unsigned)lo; }
        { int lo = __shfl_xor((int)(unsigned)(k1 & 0xFFFFFFFFull), m), hi = __shfl_xor((int)(unsigned)(k1 >> 32), m);
          e1 = ((unsigned long long)(unsigned)hi << 32) | (unsigned)lo; }
        { int lo = __shfl_xor((int)(unsigned)(k2 & 0xFFFFFFFFull), m), hi = __shfl_xor((int)(unsigned)(k2 >> 32), m);
          e2 = ((unsigned long long)(unsigned)hi << 32) | (unsigned)lo; }
        unsigned long long t0, t1;
        t0 = k0 > e0 ? k0 : e0; k0 = k0 < e0 ? k0 : e0; t1 = k1 > t0 ? k1 : t0; k1 = k1 < t0 ? k1 : t0; k2 = k2 < t1 ? k2 : t1;
        t0 = k0 > e1 ? k0 : e1; k0 = k0 < e1 ? k0 : e1; t1 = k1 > t0 ? k1 : t0; k1 = k1 < t0 ? k1 : t0; k2 = k2 < t1 ? k2 : t1;
        t0 = k0 > e2 ? k0 : e2; k0 = k0 < e2 ? k0 : e2; t1 = k1 > t0 ? k1 : t0; k1 = k1 < t0 ? k1 : t0; k2 = k2 < t1 ? k2 : t1;
    }
    if (sub == 0) {
        if (PART) {
            size_t o = ((size_t)(b * N1 + n) * nslice + slice) * 3;
            pk[o] = k0; pk[o + 1] = k1; pk[o + 2] = k2;
        } else {
            float f0 = __builtin_bit_cast(float, (unsigned)(k0 >> 32));
            float f1 = __builtin_bit_cast(float, (unsigned)(k1 >> 32));
            float f2 = __builtin_bit_cast(float, (unsigned)(k2 >> 32));
            float w0 = 1.f / (f0 + 1e-8f), w1 = 1.f / (f1 + 1e-8f), w2 = 1.f / (f2 + 1e-8f);
            float s = 1.f / (w0 + w1 + w2);
            size_t o = ((size_t)b * N1 + n) * 3;
            idx[o] = (int)(unsigned)(k0 & 0xFFFFFFFFull);
            idx[o + 1] = (int)(unsigned)(k1 & 0xFFFFFFFFull);
            idx[o + 2] = (int)(unsigned)(k2 & 0xFFFFFFFFull);
            w[o] = w0 * s; w[o + 1] = w1 * s; w[o + 2] = w2 * s;
        }
    }
}

// ================ prep: fused transposes(+cls) | KNN slices | input-only weight preps ================
__global__ __launch_bounds__(256) void prep(const float* __restrict__ f1,
                                            const float* __restrict__ f2,
                                            const float* __restrict__ f3,
                                            const float* __restrict__ f4,
                                            unsigned short* __restrict__ F1T,
                                            unsigned short* __restrict__ F2T,
                                            unsigned short* __restrict__ F3T,
                                            unsigned short* __restrict__ F4T,
                                            const int* __restrict__ lbl,
                                            const float* __restrict__ Wc1,
                                            const float* __restrict__ gc,
                                            const float* __restrict__ bc,
                                            const float* __restrict__ Wc2,
                                            const float* __restrict__ p1,
                                            const float* __restrict__ p2,
                                            const float* __restrict__ p3,
                                            const float* __restrict__ p4,
                                            int* __restrict__ idx1, float* __restrict__ w1,
                                            int* __restrict__ idx2, float* __restrict__ w2,
                                            unsigned long long* __restrict__ pk0,
                                            const float* __restrict__ Ws2a,
                                            unsigned short* __restrict__ WI2, float* __restrict__ BIA2,
                                            unsigned short* __restrict__ WS2, float* __restrict__ BIS2,
                                            const float* __restrict__ Ws1a,
                                            unsigned short* __restrict__ WS1, float* __restrict__ BIS1,
                                            const float* __restrict__ Ws0a,
                                            unsigned short* __restrict__ WS0, float* __restrict__ BIS0) {
    __shared__ float t[32][33];
    __shared__ float clsv[32];
    __shared__ float hsh[4][64];
    __shared__ float actsh[4][64];
    __shared__ float spx[8 * 72], spy[8 * 72], spz[8 * 72];
    int bx = blockIdx.x, b = blockIdx.y;
    int tid = threadIdx.x;

    if (bx >= 3024) {  // weight-prep segments (input-only, no BN fold -> bias 0)
        if (b != 0) return;
        int wx = bx - 3024;
        const float* W; unsigned short* Wb; float* bias; int Ktot, kOff, Ks, m;
        if (wx < 512)       { W = Ws2a; Wb = WI2; bias = BIA2; Ktot = 1536; kOff = 512; Ks = 1024; m = wx; }
        else if (wx < 1024) { W = Ws2a; Wb = WS2; bias = BIS2; Ktot = 1536; kOff = 0;   Ks = 512;  m = wx - 512; }
        else if (wx < 1280) { W = Ws1a; Wb = WS1; bias = BIS1; Ktot = 768;  kOff = 0;   Ks = 256;  m = wx - 1024; }
        else                { W = Ws0a; Wb = WS0; bias = BIS0; Ktot = 384;  kOff = 0;   Ks = 128;  m = wx - 1280; }
        for (int k = tid; k < Ks; k += 256)
            Wb[(size_t)m * Ks + k] = f2bf(W[(size_t)m * Ktot + kOff + k]);
        if (tid == 0) bias[m] = 0.f;
        return;
    }
    if (bx >= 1920) {  // KNN segments
        int kx = bx - 1920;
        if (kx < 16)      knn_body<128, 16, 24, false>(p3, p4, 512, 128, kx, 0, b, idx2, w2, nullptr, 1, spx, spy, spz);
        else if (kx < 80) knn_body<512, 64, 72, false>(p2, p3, 2048, 512, kx - 16, 0, b, idx1, w1, nullptr, 1, spx, spy, spz);
        else {
            int u = kx - 80;
            knn_body<512, 64, 72, true>(p1, p2, 8192, 2048, u >> 2, u & 3, b, nullptr, nullptr, pk0, 4, spx, spy, spz);
        }
        return;
    }
    // transpose segments
    const float* in; unsigned short* out; int C, N, nx, seg; bool docls = false;
    if (bx < 128)      { in = f4; out = F4T; C = 1024; N = 128;  nx = 4;   seg = bx; }
    else if (bx < 384) { in = f3; out = F3T; C = 512;  N = 512;  nx = 16;  seg = bx - 128; }
    else if (bx < 896) { in = f2; out = F2T; C = 256;  N = 2048; nx = 64;  seg = bx - 384; }
    else               { in = f1; out = F1T; C = 128;  N = 8192; nx = 256; seg = bx - 896; docls = true; }
    int n0 = (seg % nx) * 32, c0 = (seg / nx) * 32;
    if (docls) {
        { int b2 = tid >> 6, c = tid & 63; hsh[b2][c] = Wc1[c * 16 + lbl[b2]]; }
        __syncthreads();
        if (tid < 64) {
            int c = tid;
            float m = 0.f;
            for (int b2 = 0; b2 < 4; b2++) m += hsh[b2][c];
            m *= 0.25f;
            float v = 0.f;
            for (int b2 = 0; b2 < 4; b2++) { float d = hsh[b2][c] - m; v += d * d; }
            v *= 0.25f;
            float sc = gc[c] * rsqrtf(v + BN_EPS);
            float sh = bc[c] - m * sc;
            for (int b2 = 0; b2 < 4; b2++) {
                float x = hsh[b2][c] * sc + sh;
                actsh[b2][c] = 0.5f * x * (1.f + erff(x * 0.70710678118654752f));
            }
        }
        __syncthreads();
        if (tid < 32) {
            float s = 0.f;
            for (int c = 0; c < 64; c++) s += Wc2[(size_t)(c0 + tid) * 64 + c] * actsh[b][c];
            clsv[tid] = s;
        }
        __syncthreads();
    }
    int i = tid & 31, jj = tid >> 5;
#pragma unroll
    for (int j = jj; j < 32; j += 8) {
        float v = in[((size_t)b * C + c0 + j) * N + n0 + i];
        if (docls) v += clsv[j];
        t[j][i] = v;
    }
    __syncthreads();
    int j2 = tid & 31, i2b = tid >> 5;
#pragma unroll
    for (int i2 = i2b; i2 < 32; i2 += 8)
        out[((size_t)b * N + n0 + i2) * C + c0 + j2] = f2bf(t[j2][i2]);
}

// ================ 3-NN merge: combine 4 slice-partials per query (exact u64 order) ================
__global__ __launch_bounds__(256) void knn_merge(const unsigned long long* __restrict__ pk,
                                                 int* __restrict__ idx, float* __restrict__ w,
                                                 int NQ) {
    int q = blockIdx.x * 256 + threadIdx.x;
    if (q >= NQ) return;
    const unsigned long long* p = pk + (size_t)q * 12;
    unsigned long long k0 = ~0ull, k1 = ~0ull, k2 = ~0ull;
#pragma unroll
    for (int i = 0; i < 12; i++) {
        unsigned long long c = p[i];
        unsigned long long t0 = k0 > c ? k0 : c; k0 = k0 < c ? k0 : c;
        unsigned long long t1 = k1 > t0 ? k1 : t0; k1 = k1 < t0 ? k1 : t0;
        k2 = k2 < t1 ? k2 : t1;
    }
    float f0 = __builtin_bit_cast(float, (unsigned)(k0 >> 32));
    float f1 = __builtin_bit_cast(float, (unsigned)(k1 >> 32));
    float f2 = __builtin_bit_cast(float, (unsigned)(k2 >> 32));
    float w0 = 1.f / (f0 + 1e-8f), w1 = 1.f / (f1 + 1e-8f), w2 = 1.f / (f2 + 1e-8f);
    float s = 1.f / (w0 + w1 + w2);
    size_t o = (size_t)q * 3;
    idx[o] = (int)(unsigned)(k0 & 0xFFFFFFFFull);
    idx[o + 1] = (int)(unsigned)(k1 & 0xFFFFFFFFull);
    idx[o + 2] = (int)(unsigned)(k2 & 0xFFFFFFFFull);
    w[o] = w0 * s; w[o + 1] = w1 * s; w[o + 2] = w2 * s;
}

// ================ weight prep (BN fold): slice [kOff,kOff+Ks), W*sc, bias = W.sh ================
__global__ __launch_bounds__(256) void wprep(const float* __restrict__ W,
                                             const float* __restrict__ sc,
                                             const float* __restrict__ sh,
                                             unsigned short* __restrict__ Wb,
                                             float* __restrict__ bias,
                                             int Ktot, int kOff, int Ks) {
    int m = blockIdx.x;
    int tid = threadIdx.x;
    float bsum = 0.f;
    for (int k = tid; k < Ks; k += 256) {
        float wv = W[(size_t)m * Ktot + kOff + k];
        Wb[(size_t)m * Ks + k] = f2bf(wv * sc[k]);
        bsum += wv * sh[k];
    }
    __shared__ float ls[256];
    ls[tid] = bsum;
    __syncthreads();
    for (int o = 128; o > 0; o >>= 1) {
        if (tid < o) ls[tid] += ls[tid + o];
        __syncthreads();
    }
    if (tid == 0) bias[m] = ls[0];
}

// ================ bf16 MFMA GEMM 64x64, dbuf + global_load_lds + counted vmcnt ================
// GATHER: epilogue adds interp gather from G (conv'd sparse). WRSTATS: write per-block partial stats.
template<bool GATHER, bool WRSTATS>
__global__ __launch_bounds__(256) void gemm64(const unsigned short* __restrict__ XT,
                                              const unsigned short* __restrict__ Wb,
                                              const float* __restrict__ bias,
                                              const unsigned short* __restrict__ G,
                                              const int* __restrict__ gidx,
                                              const float* __restrict__ gw,
                                              int n1shift, int N2loc,
                                              unsigned short* __restrict__ OutT,
                                              float* __restrict__ ps,
                                              int BN, int K, int M) {
    __shared__ unsigned short As[2][64 * 32];
    __shared__ unsigned short Bs[2][64 * 32];
    __shared__ float sred[2][2][32][2];
    int tid = threadIdx.x;
    int lane = tid & 63, wid = tid >> 6;
    int wn = wid & 1, wm = wid >> 1;
    int bx = blockIdx.x, by = blockIdx.y;

    int srow = (wid << 4) + (lane >> 2);
    int skcol = (lane & 3) << 3;
    const unsigned short* gA = XT + (size_t)(bx * 64 + srow) * K + skcol;
    const unsigned short* gB = Wb + (size_t)(by * 64 + srow) * K + skcol;

    int r16 = lane & 15, q = lane >> 4;
    f32x4 acc[2][2];
#pragma unroll
    for (int i = 0; i < 2; i++)
#pragma unroll
        for (int j = 0; j < 2; j++) acc[i][j] = (f32x4)0.f;

    int nt = K >> 5;
    gload16(gA, &As[0][wid * 512]);
    gload16(gB, &Bs[0][wid * 512]);

    for (int t = 0; t < nt; t++) {
        int cur = t & 1;
        if (t + 1 < nt) {
            int k0 = (t + 1) << 5;
            gload16(gA + k0, &As[cur ^ 1][wid * 512]);
            gload16(gB + k0, &Bs[cur ^ 1][wid * 512]);
            asm volatile("s_waitcnt vmcnt(2)" ::: "memory");
        } else {
            asm volatile("s_waitcnt vmcnt(0)" ::: "memory");
        }
        __syncthreads();
        s16x8 afr[2], bfr[2];
        afr[0] = *(const s16x8*)&As[cur][(wn * 32 + r16) * 32 + q * 8];
        afr[1] = *(const s16x8*)&As[cur][(wn * 32 + 16 + r16) * 32 + q * 8];
        bfr[0] = *(const s16x8*)&Bs[cur][(wm * 32 + r16) * 32 + q * 8];
        bfr[1] = *(const s16x8*)&Bs[cur][(wm * 32 + 16 + r16) * 32 + q * 8];
        asm volatile("s_waitcnt lgkmcnt(0)" ::: "memory");
        __builtin_amdgcn_sched_barrier(0);
        __syncthreads();
#pragma unroll
        for (int i = 0; i < 2; i++)
#pragma unroll
            for (int j = 0; j < 2; j++)
                acc[i][j] = __builtin_amdgcn_mfma_f32_16x16x32_bf16(afr[i], bfr[j], acc[i][j], 0, 0, 0);
    }

    if (GATHER) {
#pragma unroll
        for (int i = 0; i < 2; i++)
#pragma unroll
            for (int rr = 0; rr < 4; rr++) {
                int R = bx * 64 + wn * 32 + i * 16 + q * 4 + rr;
                size_t ob = (size_t)R * 3;
                int i0 = gidx[ob], i1 = gidx[ob + 1], i2 = gidx[ob + 2];
                float w0 = gw[ob], w1 = gw[ob + 1], w2 = gw[ob + 2];
                size_t gbase = (size_t)(R >> n1shift) * N2loc;
                const unsigned short* g0 = G + (gbase + i0) * M + by * 64;
                const unsigned short* g1 = G + (gbase + i1) * M + by * 64;
                const unsigned short* g2 = G + (gbase + i2) * M + by * 64;
#pragma unroll
                for (int j = 0; j < 2; j++) {
                    int mcol = wm * 32 + j * 16 + r16;
                    acc[i][j][rr] += w0 * bf2f(g0[mcol]) + w1 * bf2f(g1[mcol]) + w2 * bf2f(g2[mcol]);
                }
            }
    }

    int mc0 = by * 64 + wm * 32 + r16;
    float bv[2] = { bias[mc0], bias[mc0 + 16] };
    unsigned short* Ob = OutT + (size_t)(bx * 64) * M + by * 64;
    float s[2] = {0.f, 0.f}, qq[2] = {0.f, 0.f};
#pragma unroll
    for (int i = 0; i < 2; i++) {
#pragma unroll
        for (int j = 0; j < 2; j++) {
            int mcol = wm * 32 + j * 16 + r16;
#pragma unroll
            for (int r = 0; r < 4; r++) {
                float v = acc[i][j][r] + bv[j];
                s[j] += v; qq[j] += v * v;
                int n = wn * 32 + i * 16 + q * 4 + r;
                Ob[(size_t)n * M + mcol] = f2bf(v);
            }
        }
    }
    if (WRSTATS) {
#pragma unroll
        for (int j = 0; j < 2; j++) {
            s[j] += __shfl_xor(s[j], 16); s[j] += __shfl_xor(s[j], 32);
            qq[j] += __shfl_xor(qq[j], 16); qq[j] += __shfl_xor(qq[j], 32);
        }
        if (lane < 16) {
#pragma unroll
            for (int j = 0; j < 2; j++) {
                sred[wn][wm][j * 16 + lane][0] = s[j];
                sred[wn][wm][j * 16 + lane][1] = qq[j];
            }
        }
        __syncthreads();
        if (tid < 64) {
            int wmm = tid >> 5, c = tid & 31;
            float ssum = sred[0][wmm][c][0] + sred[1][wmm][c][0];
            float qsum = sred[0][wmm][c][1] + sred[1][wmm][c][1];
            size_t blin = (size_t)by * gridDim.x + bx;
            ps[blin * 128 + tid * 2] = ssum;
            ps[blin * 128 + tid * 2 + 1] = qsum;
        }
    }
}

// ================ finalize BN: one block per channel ================
__global__ __launch_bounds__(256) void bn_finalize(const float* __restrict__ ps,
                                                   const float* __restrict__ g,
                                                   const float* __restrict__ bb,
                                                   float* __restrict__ sc,
                                                   float* __restrict__ sh,
                                                   int gx, int Npts) {
    int m = blockIdx.x;
    int by = m >> 6, ch = m & 63;
    float s = 0.f, q = 0.f;
    for (int bxi = threadIdx.x; bxi < gx; bxi += 256) {
        size_t blin = (size_t)by * gx + bxi;
        s += ps[blin * 128 + ch * 2];
        q += ps[blin * 128 + ch * 2 + 1];
    }
    __shared__ float ls[256], lq[256];
    ls[threadIdx.x] = s; lq[threadIdx.x] = q;
    __syncthreads();
    for (int o = 128; o > 0; o >>= 1) {
        if (threadIdx.x < o) { ls[threadIdx.x] += ls[threadIdx.x + o]; lq[threadIdx.x] += lq[threadIdx.x + o]; }
        __syncthreads();
    }
    if (threadIdx.x == 0) {
        float inv = 1.f / (float)Npts;
        float mean = ls[0] * inv;
        float var = fmaxf(lq[0] * inv - mean * mean, 0.f);
        float scale = g[m] * rsqrtf(var + BN_EPS);
        sc[m] = scale;
        sh[m] = bb[m] - mean * scale;
    }
}

// ================ final: (B,N,M) bf16 -> (B,M,N) fp32 with BN affine ================
__global__ __launch_bounds__(256) void out_bn_tr(const unsigned short* __restrict__ in,
                                                 float* __restrict__ out,
                                                 const float* __restrict__ sc,
                                                 const float* __restrict__ sh,
                                                 int M, int N) {
    __shared__ float t[32][33];
    int b = blockIdx.z;
    int n0 = blockIdx.x * 32, m0 = blockIdx.y * 32;
    int j = threadIdx.x & 31, ii = threadIdx.x >> 5;
#pragma unroll
    for (int i = ii; i < 32; i += 8)
        t[i][j] = bf2f(in[((size_t)b * N + n0 + i) * M + m0 + j]);
    __syncthreads();
    int i2 = threadIdx.x & 31, j2b = threadIdx.x >> 5;
#pragma unroll
    for (int j2 = j2b; j2 < 32; j2 += 8)
        out[((size_t)b * M + m0 + j2) * N + n0 + i2] = t[i2][j2] * sc[m0 + j2] + sh[m0 + j2];
}

extern "C" void kernel_launch(void* const* d_in, const int* in_sizes, int n_in,
                              void* d_out, int out_size, void* d_ws, size_t ws_size,
                              hipStream_t stream) {
    const float* p1 = (const float*)d_in[1];
    const float* p2 = (const float*)d_in[2];
    const float* p3 = (const float*)d_in[3];
    const float* p4 = (const float*)d_in[4];
    const float* f1 = (const float*)d_in[5];
    const float* f2 = (const float*)d_in[6];
    const float* f3 = (const float*)d_in[7];
    const float* f4 = (const float*)d_in[8];
    const int* cls = (const int*)d_in[9];
    const float* Wc1 = (const float*)d_in[10];
    const float* gc  = (const float*)d_in[11];
    const float* bc  = (const float*)d_in[12];
    const float* Wc2 = (const float*)d_in[13];
    const float* Ws2a = (const float*)d_in[14];
    const float* gs2a = (const float*)d_in[15];
    const float* bs2a = (const float*)d_in[16];
    const float* Ws2b = (const float*)d_in[17];
    const float* gs2b = (const float*)d_in[18];
    const float* bs2b = (const float*)d_in[19];
    const float* Ws1a = (const float*)d_in[20];
    const float* gs1a = (const float*)d_in[21];
    const float* bs1a = (const float*)d_in[22];
    const float* Ws1b = (const float*)d_in[23];
    const float* gs1b = (const float*)d_in[24];
    const float* bs1b = (const float*)d_in[25];
    const float* Ws0a = (const float*)d_in[26];
    const float* gs0a = (const float*)d_in[27];
    const float* bs0a = (const float*)d_in[28];
    const float* Ws0b = (const float*)d_in[29];
    const float* gs0b = (const float*)d_in[30];
    const float* bs0b = (const float*)d_in[31];

    char* ws = (char*)d_ws;
    size_t off = 0;
    auto alloc = [&](size_t bytes) { char* p = ws + off; off += (bytes + 255) & ~(size_t)255; return p; };
    unsigned short* F4T = (unsigned short*)alloc((size_t)4 * 128 * 1024 * 2);
    unsigned short* F3T = (unsigned short*)alloc((size_t)4 * 512 * 512 * 2);
    unsigned short* F2T = (unsigned short*)alloc((size_t)4 * 2048 * 256 * 2);
    unsigned short* F1T = (unsigned short*)alloc((size_t)4 * 8192 * 128 * 2);
    unsigned short* G2T = (unsigned short*)alloc((size_t)4 * 128 * 512 * 2);
    unsigned short* G1T = (unsigned short*)alloc((size_t)4 * 512 * 256 * 2);
    unsigned short* G0T = (unsigned short*)alloc((size_t)4 * 2048 * 128 * 2);
    unsigned short* YA  = (unsigned short*)alloc((size_t)4 * 8192 * 128 * 2);
    unsigned short* FN2 = (unsigned short*)alloc((size_t)4 * 512 * 512 * 2);
    unsigned short* FN1 = (unsigned short*)alloc((size_t)4 * 2048 * 256 * 2);
    unsigned short* XO  = (unsigned short*)alloc((size_t)4 * 8192 * 128 * 2);
    unsigned short* WI2 = (unsigned short*)alloc((size_t)512 * 1024 * 2);
    unsigned short* WS2 = (unsigned short*)alloc((size_t)512 * 512 * 2);
    unsigned short* WB2b = (unsigned short*)alloc((size_t)512 * 512 * 2);
    unsigned short* WI1 = (unsigned short*)alloc((size_t)256 * 512 * 2);
    unsigned short* WS1 = (unsigned short*)alloc((size_t)256 * 256 * 2);
    unsigned short* WB1b = (unsigned short*)alloc((size_t)256 * 256 * 2);
    unsigned short* WI0 = (unsigned short*)alloc((size_t)128 * 256 * 2);
    unsigned short* WS0 = (unsigned short*)alloc((size_t)128 * 128 * 2);
    unsigned short* WB0b = (unsigned short*)alloc((size_t)128 * 128 * 2);
    float* BIA2 = (float*)alloc(512 * 4); float* BIS2 = (float*)alloc(512 * 4);
    float* BI2b = (float*)alloc(512 * 4);
    float* BIA1 = (float*)alloc(256 * 4); float* BIS1 = (float*)alloc(256 * 4);
    float* BI1b = (float*)alloc(256 * 4);
    float* BIA0 = (float*)alloc(128 * 4); float* BIS0 = (float*)alloc(128 * 4);
    float* BI0b = (float*)alloc(128 * 4);
    int*   IDX0 = (int*)alloc((size_t)4 * 8192 * 3 * 4);
    float* WGT0 = (float*)alloc((size_t)4 * 8192 * 3 * 4);
    int*   IDX1 = (int*)alloc((size_t)4 * 2048 * 3 * 4);
    float* WGT1 = (float*)alloc((size_t)4 * 2048 * 3 * 4);
    int*   IDX2 = (int*)alloc((size_t)4 * 512 * 3 * 4);
    float* WGT2 = (float*)alloc((size_t)4 * 512 * 3 * 4);
    unsigned long long* PK0 = (unsigned long long*)alloc((size_t)4 * 8192 * 4 * 3 * 8);
    float* PS = (float*)alloc((size_t)1024 * 128 * 4);
    float* SC2a = (float*)alloc(512 * 4); float* SH2a = (float*)alloc(512 * 4);
    float* SC2b = (float*)alloc(512 * 4); float* SH2b = (float*)alloc(512 * 4);
    float* SC1a = (float*)alloc(512 * 4); float* SH1a = (float*)alloc(512 * 4);
    float* SC1b = (float*)alloc(512 * 4); float* SH1b = (float*)alloc(512 * 4);
    float* SC0a = (float*)alloc(512 * 4); float* SH0a = (float*)alloc(512 * 4);
    float* SC0b = (float*)alloc(512 * 4); float* SH0b = (float*)alloc(512 * 4);
    float* OUT = (float*)d_out;

    // 1) all input-only work in one dispatch
    prep<<<dim3(4432, 4), 256, 0, stream>>>(f1, f2, f3, f4, F1T, F2T, F3T, F4T,
                                            cls, Wc1, gc, bc, Wc2,
                                            p1, p2, p3, p4,
                                            IDX1, WGT1, IDX2, WGT2, PK0,
                                            Ws2a, WI2, BIA2, WS2, BIS2,
                                            Ws1a, WS1, BIS1, Ws0a, WS0, BIS0);
    knn_merge<<<(4 * 8192) / 256, 256, 0, stream>>>(PK0, IDX0, WGT0, 4 * 8192);

    // ---- stage s2
    gemm64<false, false><<<dim3(8, 8), 256, 0, stream>>>(F4T, WI2, BIA2, nullptr, nullptr, nullptr, 0, 0,
                                                         G2T, nullptr, 512, 1024, 512);
    gemm64<true, true><<<dim3(32, 8), 256, 0, stream>>>(F3T, WS2, BIS2, G2T, IDX2, WGT2, 9, 128,
                                                        YA, PS, 2048, 512, 512);
    bn_finalize<<<512, 256, 0, stream>>>(PS, gs2a, bs2a, SC2a, SH2a, 32, 2048);
    wprep<<<512, 256, 0, stream>>>(Ws2b, SC2a, SH2a, WB2b, BI2b, 512, 0, 512);
    gemm64<false, true><<<dim3(32, 8), 256, 0, stream>>>(YA, WB2b, BI2b, nullptr, nullptr, nullptr, 0, 0,
                                                         FN2, PS, 2048, 512, 512);
    bn_finalize<<<512, 256, 0, stream>>>(PS, gs2b, bs2b, SC2b, SH2b, 32, 2048);

    // ---- stage s1
    wprep<<<256, 256, 0, stream>>>(Ws1a, SC2b, SH2b, WI1, BIA1, 768, 256, 512);
    gemm64<false, false><<<dim3(32, 4), 256, 0, stream>>>(FN2, WI1, BIA1, nullptr, nullptr, nullptr, 0, 0,
                                                          G1T, nullptr, 2048, 512, 256);
    gemm64<true, true><<<dim3(128, 4), 256, 0, stream>>>(F2T, WS1, BIS1, G1T, IDX1, WGT1, 11, 512,
                                                         YA, PS, 8192, 256, 256);
    bn_finalize<<<256, 256, 0, stream>>>(PS, gs1a, bs1a, SC1a, SH1a, 128, 8192);
    wprep<<<256, 256, 0, stream>>>(Ws1b, SC1a, SH1a, WB1b, BI1b, 256, 0, 256);
    gemm64<false, true><<<dim3(128, 4), 256, 0, stream>>>(YA, WB1b, BI1b, nullptr, nullptr, nullptr, 0, 0,
                                                          FN1, PS, 8192, 256, 256);
    bn_finalize<<<256, 256, 0, stream>>>(PS, gs1b, bs1b, SC1b, SH1b, 128, 8192);

    // ---- stage s0
    wprep<<<128, 256, 0, stream>>>(Ws0a, SC1b, SH1b, WI0, BIA0, 384, 128, 256);
    gemm64<false, false><<<dim3(128, 2), 256, 0, stream>>>(FN1, WI0, BIA0, nullptr, nullptr, nullptr, 0, 0,
                                                           G0T, nullptr, 8192, 256, 128);
    gemm64<true, true><<<dim3(512, 2), 256, 0, stream>>>(F1T, WS0, BIS0, G0T, IDX0, WGT0, 13, 2048,
                                                         YA, PS, 32768, 128, 128);
    bn_finalize<<<128, 256, 0, stream>>>(PS, gs0a, bs0a, SC0a, SH0a, 512, 32768);
    wprep<<<128, 256, 0, stream>>>(Ws0b, SC0a, SH0a, WB0b, BI0b, 128, 0, 128);
    gemm64<false, true><<<dim3(512, 2), 256, 0, stream>>>(YA, WB0b, BI0b, nullptr, nullptr, nullptr, 0, 0,
                                                          XO, PS, 32768, 128, 128);
    bn_finalize<<<128, 256, 0, stream>>>(PS, gs0b, bs0b, SC0b, SH0b, 512, 32768);

    out_bn_tr<<<dim3(8192 / 32, 128 / 32, 4), 256, 0, stream>>>(XO, OUT, SC0b, SH0b, 128, 8192);
}